// Round 2
// baseline (400.090 us; speedup 1.0000x reference)
//
#include <hip/hip_runtime.h>
#include <hip/hip_bf16.h>

// ---------------------------------------------------------------------------
// RecursiveSortNet — bf16 MFMA pipeline, u16-key packed bitonic sort:
//   sort: round x to bf16 (monotone => commutes with sort), map to
//         order-preserving u16 keys, 3x bitonic-64 with v_pk_min/max_u16
//   h1 = relu(xs @ W1^T + b1)   bf16 MFMA, fp32 acc
//   h2 = relu(h1 @ W2^T + b2)
//   out =      h2 @ W3^T + b3   fp32 out
//
// R1: replaced sort __syncthreads with intra-wave lgkmcnt waits (waves own
//     disjoint LDS). 146 -> 91 us, VALUBusy 30 -> 49%.
// R2: sort ILP-2 — each wave sorts TWO independent matrices; second
//     matrix's LDS reads land under first matrix's sortnet => per-phase
//     LDS latency paid once per 2 matrices. 64-thread blocks (1 wave),
//     9 blocks/CU by LDS. Also merged 3 cvt launches into 1.
// ---------------------------------------------------------------------------

#define B_DIM 8192
#define D_DIM 4096
#define H1_DIM 512
#define H2_DIM 256

typedef unsigned short u16;
typedef __attribute__((ext_vector_type(2))) unsigned short u16x2;
typedef __attribute__((ext_vector_type(2))) short i16x2;
typedef __attribute__((ext_vector_type(8))) short bf16x8;
typedef __attribute__((ext_vector_type(4))) float f32x4;

// Intra-wave LDS ordering: all prior DS ops complete before any later DS op
// issues; "memory" clobber stops compiler reordering across the point.
#define WAVE_SYNC() asm volatile("s_waitcnt lgkmcnt(0)" ::: "memory")

__device__ __forceinline__ unsigned short f2bf(float f) {
    union { float f; unsigned u; } v{f};
    unsigned r = v.u + 0x7FFF + ((v.u >> 16) & 1);   // RNE, finite inputs
    return (unsigned short)(r >> 16);
}
// bf16 bits -> order-preserving u16 key
__device__ __forceinline__ u16 fkey(float f) {
    u16 bf = f2bf(f);
    u16 m  = (u16)(((short)bf) >> 15);               // 0xFFFF if negative
    return (u16)(bf ^ (m | 0x8000));
}
__device__ __forceinline__ u16x2 mk2(u16 a, u16 b) { u16x2 r; r.x = a; r.y = b; return r; }

#if defined(__has_builtin) && __has_builtin(__builtin_elementwise_min)
__device__ __forceinline__ u16x2 pkmin(u16x2 a, u16x2 b) { return __builtin_elementwise_min(a, b); }
__device__ __forceinline__ u16x2 pkmax(u16x2 a, u16x2 b) { return __builtin_elementwise_max(a, b); }
#else
__device__ __forceinline__ u16x2 pkmin(u16x2 a, u16x2 b) {
    return mk2(a.x < b.x ? a.x : b.x, a.y < b.y ? a.y : b.y);
}
__device__ __forceinline__ u16x2 pkmax(u16x2 a, u16x2 b) {
    return mk2(a.x > b.x ? a.x : b.x, a.y > b.y ? a.y : b.y);
}
#endif

// Bitonic sort of 64 u16 keys held as 32 packed regs, reg p = (elem p, elem p+32).
__device__ __forceinline__ void sortnet(u16x2 v[32]) {
#pragma unroll
    for (int k = 2; k <= 64; k <<= 1) {
#pragma unroll
        for (int j = k >> 1; j >= 1; j >>= 1) {
            if (j == 32) {                     // k==64 only, ascending
#pragma unroll
                for (int p = 0; p < 32; ++p) {
                    u16x2 sw = mk2(v[p].y, v[p].x);
                    u16x2 mn = pkmin(v[p], sw), mx = pkmax(v[p], sw);
                    v[p] = mk2(mn.x, mx.y);
                }
            } else {
#pragma unroll
                for (int p = 0; p < 32; ++p) {
                    if (p & j) continue;
                    const int q = p | j;
                    const bool upx = ((p & k) == 0);
                    const bool upy = (((p + 32) & k) == 0);  // differs only at k==32
                    u16x2 mn = pkmin(v[p], v[q]), mx = pkmax(v[p], v[q]);
                    if (upx == upy) {
                        v[p] = upx ? mn : mx;
                        v[q] = upx ? mx : mn;
                    } else {                   // k==32: slot x asc, slot y desc
                        v[p] = mk2(mn.x, mx.y);
                        v[q] = mk2(mx.x, mn.y);
                    }
                }
            }
        }
    }
}

#define SRT 66

__device__ __forceinline__ void stage_in(const float* __restrict__ src, u16* s, int lane) {
    float4 t[16];
#pragma unroll
    for (int qq = 0; qq < 16; ++qq)
        t[qq] = *(const float4*)(src + (qq * 64 + lane) * 4);
#pragma unroll
    for (int qq = 0; qq < 16; ++qq) {
        int f = qq * 64 + lane, r = f >> 4, c0 = (f & 15) * 4;
        *(u16x2*)&s[r * SRT + c0]     = mk2(fkey(t[qq].x), fkey(t[qq].y));
        *(u16x2*)&s[r * SRT + c0 + 2] = mk2(fkey(t[qq].z), fkey(t[qq].w));
    }
}
__device__ __forceinline__ void col_read(const u16* s, int lane, u16x2 v[32]) {
#pragma unroll
    for (int p = 0; p < 32; ++p)
        v[p] = mk2(s[p * SRT + lane], s[(p + 32) * SRT + lane]);
}
__device__ __forceinline__ void perm_write(u16* s, int pos, const u16x2 v[32]) {
#pragma unroll
    for (int p = 0; p < 32; ++p) {
        s[p * SRT + pos]        = v[p].x;
        s[(p + 32) * SRT + pos] = v[p].y;
    }
}
__device__ __forceinline__ void row_read(const u16* s, int lane, u16x2 v[32]) {
#pragma unroll
    for (int p = 0; p < 32; ++p)
        v[p] = *(const u16x2*)&s[lane * SRT + p * 2];
}
__device__ __forceinline__ void row_write(u16* s, int lane, const u16x2 v[32]) {
#pragma unroll
    for (int p = 0; p < 32; ++p) {
        s[lane * SRT + p]      = v[p].x;
        s[lane * SRT + p + 32] = v[p].y;
    }
}
__device__ __forceinline__ void col_write(u16* s, int lane, const u16x2 v[32]) {
#pragma unroll
    for (int p = 0; p < 32; ++p) {
        s[p * SRT + lane]        = v[p].x;
        s[(p + 32) * SRT + lane] = v[p].y;
    }
}
__device__ __forceinline__ void unmap(u16x2 v[32]) {
#pragma unroll
    for (int p = 0; p < 32; ++p) {
        i16x2 sh = ((i16x2)v[p]) >> 15;        // 0xFFFF where key bit15 set (orig >=0)
        u16x2 m  = (u16x2)sh;
        u16x2 c8; c8.x = 0x8000; c8.y = 0x8000;
        v[p] = v[p] ^ ((~m) | c8);
    }
}
__device__ __forceinline__ void stage_out(const u16* s, u16* __restrict__ dst, int lane) {
#pragma unroll
    for (int qq = 0; qq < 16; ++qq) {
        int f = qq * 64 + lane, r = f >> 4, c0 = (f & 15) * 4;
        u16x2 a = *(const u16x2*)&s[r * SRT + c0];
        u16x2 c = *(const u16x2*)&s[r * SRT + c0 + 2];
        ushort4 o; o.x = a.x; o.y = a.y; o.z = c.x; o.w = c.y;
        *(ushort4*)(dst + f * 4) = o;
    }
}

// One wave (64 threads) sorts TWO 64x64 matrices with interleaved phases:
// matrix B's LDS reads complete under matrix A's sortnet (ILP latency hiding).
// LDS 16896 B/block -> 9 blocks/CU resident.
__global__ __launch_bounds__(64)
void sort_kernel(const float* __restrict__ x, u16* __restrict__ xs)
{
    __shared__ u16 smem[2 * 64 * SRT];
    const int lane = threadIdx.x;                // 0..63, one wave per block
    u16* s0 = smem;
    u16* s1 = smem + 64 * SRT;
    const size_t b0 = (size_t)blockIdx.x * 2;
    const float* src0 = x  + b0 * D_DIM;
    u16*         dst0 = xs + b0 * D_DIM;

    // ---- stage-in both matrices ----
    stage_in(src0,         s0, lane);
    stage_in(src0 + D_DIM, s1, lane);
    WAVE_SYNC();

    u16x2 va[32], vb[32];

    // ---- sort 1: columns ----
    col_read(s0, lane, va);
    col_read(s1, lane, vb);
    sortnet(va);
    sortnet(vb);
    WAVE_SYNC();
    {
        const int pos = (lane & 31) * 2 + (lane >> 5);
        perm_write(s0, pos, va);
        perm_write(s1, pos, vb);
    }
    WAVE_SYNC();

    // ---- sort 2: rows (permuted layout -> packed b32 reads) ----
    row_read(s0, lane, va);
    row_read(s1, lane, vb);
    sortnet(va);
    sortnet(vb);
    WAVE_SYNC();
    row_write(s0, lane, va);
    row_write(s1, lane, vb);
    WAVE_SYNC();

    // ---- sort 3: columns again ----
    col_read(s0, lane, va);
    col_read(s1, lane, vb);
    sortnet(va);
    sortnet(vb);
    unmap(va);
    unmap(vb);
    WAVE_SYNC();
    col_write(s0, lane, va);
    col_write(s1, lane, vb);
    WAVE_SYNC();

    // ---- stage-out ----
    stage_out(s0, dst0,         lane);
    stage_out(s1, dst0 + D_DIM, lane);
}

// ---------------- fp32 -> bf16 weight conversion (all 3 weights, 1 launch) --
__global__ __launch_bounds__(256)
void cvt_all(const float* __restrict__ W1, unsigned short* __restrict__ W1b,
             const float* __restrict__ W2, unsigned short* __restrict__ W2b,
             const float* __restrict__ W3, unsigned short* __restrict__ W3b)
{
    constexpr int N1 = H1_DIM * D_DIM / 4;
    constexpr int N2 = H2_DIM * H1_DIM / 4;
    constexpr int N3 = D_DIM * H2_DIM / 4;
    int i = blockIdx.x * blockDim.x + threadIdx.x;
    const float* src; unsigned short* dst; int j;
    if (i < N1)                 { src = W1; dst = W1b; j = i; }
    else if (i < N1 + N2)       { src = W2; dst = W2b; j = i - N1; }
    else if (i < N1 + N2 + N3)  { src = W3; dst = W3b; j = i - N1 - N2; }
    else return;
    float4 v = ((const float4*)src)[j];
    ushort4 o;
    o.x = f2bf(v.x); o.y = f2bf(v.y); o.z = f2bf(v.z); o.w = f2bf(v.w);
    ((ushort4*)dst)[j] = o;
}

// ---------------- bf16 MFMA GEMM: C = act(A @ W^T + bias) ------------------
template<int BM, int BN, bool RELU, bool OUT_BF16>
__global__ __launch_bounds__(256, 2)
void gemm_mfma(const unsigned short* __restrict__ A,
               const unsigned short* __restrict__ Wt,
               const float* __restrict__ bias,
               void* __restrict__ Cout, int M, int N, int K)
{
    constexpr int BK  = 64;
    constexpr int WTM = BM / 2, WTN = BN / 2;
    constexpr int FM  = WTM / 16, FN = WTN / 16;
    __shared__ unsigned short sA[BM * BK];
    __shared__ unsigned short sB[BN * BK];

    const int tid  = threadIdx.x;
    const int wave = tid >> 6;
    const int lane = tid & 63;
    const int wm   = wave >> 1, wn = wave & 1;
    const int gm0  = blockIdx.y * BM;
    const int gn0  = blockIdx.x * BN;

    const int r_in = lane >> 3;
    const int j_in = lane & 7;

    f32x4 acc[FM][FN] = {};

    for (int k0 = 0; k0 < K; k0 += BK) {
#pragma unroll
        for (int c = 0; c < BM / 32; ++c) {
            int rb  = wave * (BM / 4) + c * 8;
            int r   = rb + r_in;
            int seg = j_in ^ (r & 7);
            const unsigned short* g = A + (size_t)(gm0 + r) * K + k0 + seg * 8;
            __builtin_amdgcn_global_load_lds(
                (const __attribute__((address_space(1))) void*)g,
                (__attribute__((address_space(3))) void*)&sA[rb * 64],
                16, 0, 0);
        }
#pragma unroll
        for (int c = 0; c < BN / 32; ++c) {
            int rb  = wave * (BN / 4) + c * 8;
            int r   = rb + r_in;
            int seg = j_in ^ (r & 7);
            const unsigned short* g = Wt + (size_t)(gn0 + r) * K + k0 + seg * 8;
            __builtin_amdgcn_global_load_lds(
                (const __attribute__((address_space(1))) void*)g,
                (__attribute__((address_space(3))) void*)&sB[rb * 64],
                16, 0, 0);
        }
        __syncthreads();

#pragma unroll
        for (int ks = 0; ks < 2; ++ks) {
            bf16x8 afr[FM], bfr[FN];
#pragma unroll
            for (int i = 0; i < FM; ++i) {
                int m   = wm * WTM + i * 16 + (lane & 15);
                int seg = (ks * 4 + (lane >> 4)) ^ (m & 7);
                afr[i] = *(const bf16x8*)&sA[m * 64 + seg * 8];
            }
#pragma unroll
            for (int j = 0; j < FN; ++j) {
                int n   = wn * WTN + j * 16 + (lane & 15);
                int seg = (ks * 4 + (lane >> 4)) ^ (n & 7);
                bfr[j] = *(const bf16x8*)&sB[n * 64 + seg * 8];
            }
#pragma unroll
            for (int i = 0; i < FM; ++i)
#pragma unroll
                for (int j = 0; j < FN; ++j)
                    acc[i][j] = __builtin_amdgcn_mfma_f32_16x16x32_bf16(
                        afr[i], bfr[j], acc[i][j], 0, 0, 0);
        }
        __syncthreads();
    }

#pragma unroll
    for (int j = 0; j < FN; ++j) {
        int n = gn0 + wn * WTN + j * 16 + (lane & 15);
        float bv = bias[n];
#pragma unroll
        for (int i = 0; i < FM; ++i) {
#pragma unroll
            for (int r = 0; r < 4; ++r) {
                int m = gm0 + wm * WTM + i * 16 + (lane >> 4) * 4 + r;
                float v = acc[i][j][r] + bv;
                if (RELU) v = fmaxf(v, 0.f);
                if (OUT_BF16)
                    ((unsigned short*)Cout)[(size_t)m * N + n] = f2bf(v);
                else
                    ((float*)Cout)[(size_t)m * N + n] = v;
            }
        }
    }
}

// ---------------------------------------------------------------------------
extern "C" void kernel_launch(void* const* d_in, const int* in_sizes, int n_in,
                              void* d_out, int out_size, void* d_ws, size_t ws_size,
                              hipStream_t stream)
{
    const float* x  = (const float*)d_in[0];
    const float* W1 = (const float*)d_in[1];
    const float* b1 = (const float*)d_in[2];
    const float* W2 = (const float*)d_in[3];
    const float* b2 = (const float*)d_in[4];
    const float* W3 = (const float*)d_in[5];
    const float* b3 = (const float*)d_in[6];
    float* out = (float*)d_out;

    // xs (bf16, 64 MB) lives in d_out; GEMM3 overwrites d_out after GEMM1 read xs.
    u16* xs = (u16*)d_out;
    char* ws = (char*)d_ws;
    unsigned short* h1b = (unsigned short*)(ws);                      //  8 MB
    unsigned short* h2b = (unsigned short*)(ws + (8u  << 20));        //  4 MB
    unsigned short* W1b = (unsigned short*)(ws + (12u << 20));        //  4 MB
    unsigned short* W2b = (unsigned short*)(ws + (16u << 20));        //  0.25 MB
    unsigned short* W3b = (unsigned short*)(ws + (17u << 20));        //  2 MB

    sort_kernel<<<B_DIM / 2, 64, 0, stream>>>(x, xs);

    {
        constexpr int NT = (H1_DIM * D_DIM + H2_DIM * H1_DIM + D_DIM * H2_DIM) / 4;
        cvt_all<<<(NT + 255) / 256, 256, 0, stream>>>(W1, W1b, W2, W2b, W3, W3b);
    }

    // h1 = relu(xs @ W1^T + b1)  [8192 x 512, K=4096]  tile 128x64
    gemm_mfma<128, 64, true, true>
        <<<dim3(H1_DIM / 64, B_DIM / 128), 256, 0, stream>>>(
            xs, W1b, b1, h1b, B_DIM, H1_DIM, D_DIM);

    // h2 = relu(h1 @ W2^T + b2)  [8192 x 256, K=512]   tile 128x64
    gemm_mfma<128, 64, true, true>
        <<<dim3(H2_DIM / 64, B_DIM / 128), 256, 0, stream>>>(
            h1b, W2b, b2, h2b, B_DIM, H2_DIM, H1_DIM);

    // out = h2 @ W3^T + b3       [8192 x 4096, K=256]  tile 128x128
    gemm_mfma<128, 128, false, false>
        <<<dim3(D_DIM / 128, B_DIM / 128), 256, 0, stream>>>(
            h2b, W3b, b3, out, B_DIM, D_DIM, H2_DIM);
}

// Round 3
// 380.578 us; speedup vs baseline: 1.0513x; 1.0513x over previous
//
#include <hip/hip_runtime.h>
#include <hip/hip_bf16.h>

// ---------------------------------------------------------------------------
// RecursiveSortNet — bf16 MFMA pipeline, u16-key packed bitonic sort:
//   sort: round x to bf16 (monotone => commutes with sort), map to
//         order-preserving u16 keys, 3x bitonic-64 with v_pk_min/max_u16
//   h1 = relu(xs @ W1^T + b1)   bf16 MFMA, fp32 acc
//   h2 = relu(h1 @ W2^T + b2)
//   out =      h2 @ W3^T + b3   fp32 out
//
// R1: sort __syncthreads -> intra-wave lgkmcnt fences. 146 -> 91 us.
// R2: ILP-2 with 2 LDS buffers/wave: REGRESSED (118 us) — LDS capacity
//     halved occupancy (18 -> 9 waves/CU).
// R3: ILP-2 with ONE shared buffer/wave: the two matrices time-share the
//     buffer; each boundary's writes for matrix X issue in the same
//     fence-region as matrix Y's sortnet (VALU hides DS). LDS/wave back to
//     8448 B -> 18 waves/CU AND ILP-2. Weight cvt fused into sort launch
//     as extra blocks. GEMM grids swapped to (M,N) so A-panel siblings
//     share an XCD (L2 locality).
// ---------------------------------------------------------------------------

#define B_DIM 8192
#define D_DIM 4096
#define H1_DIM 512
#define H2_DIM 256

typedef unsigned short u16;
typedef __attribute__((ext_vector_type(2))) unsigned short u16x2;
typedef __attribute__((ext_vector_type(2))) short i16x2;
typedef __attribute__((ext_vector_type(8))) short bf16x8;
typedef __attribute__((ext_vector_type(4))) float f32x4;

// Intra-wave LDS ordering: all prior DS ops complete before anything later
// issues; "memory" clobber stops compiler reordering memory ops across it.
#define WAVE_SYNC() asm volatile("s_waitcnt lgkmcnt(0)" ::: "memory")

__device__ __forceinline__ unsigned short f2bf(float f) {
    union { float f; unsigned u; } v{f};
    unsigned r = v.u + 0x7FFF + ((v.u >> 16) & 1);   // RNE, finite inputs
    return (unsigned short)(r >> 16);
}
// bf16 bits -> order-preserving u16 key
__device__ __forceinline__ u16 fkey(float f) {
    u16 bf = f2bf(f);
    u16 m  = (u16)(((short)bf) >> 15);               // 0xFFFF if negative
    return (u16)(bf ^ (m | 0x8000));
}
__device__ __forceinline__ u16x2 mk2(u16 a, u16 b) { u16x2 r; r.x = a; r.y = b; return r; }

#if defined(__has_builtin) && __has_builtin(__builtin_elementwise_min)
__device__ __forceinline__ u16x2 pkmin(u16x2 a, u16x2 b) { return __builtin_elementwise_min(a, b); }
__device__ __forceinline__ u16x2 pkmax(u16x2 a, u16x2 b) { return __builtin_elementwise_max(a, b); }
#else
__device__ __forceinline__ u16x2 pkmin(u16x2 a, u16x2 b) {
    return mk2(a.x < b.x ? a.x : b.x, a.y < b.y ? a.y : b.y);
}
__device__ __forceinline__ u16x2 pkmax(u16x2 a, u16x2 b) {
    return mk2(a.x > b.x ? a.x : b.x, a.y > b.y ? a.y : b.y);
}
#endif

// Bitonic sort of 64 u16 keys held as 32 packed regs, reg p = (elem p, elem p+32).
__device__ __forceinline__ void sortnet(u16x2 v[32]) {
#pragma unroll
    for (int k = 2; k <= 64; k <<= 1) {
#pragma unroll
        for (int j = k >> 1; j >= 1; j >>= 1) {
            if (j == 32) {                     // k==64 only, ascending
#pragma unroll
                for (int p = 0; p < 32; ++p) {
                    u16x2 sw = mk2(v[p].y, v[p].x);
                    u16x2 mn = pkmin(v[p], sw), mx = pkmax(v[p], sw);
                    v[p] = mk2(mn.x, mx.y);
                }
            } else {
#pragma unroll
                for (int p = 0; p < 32; ++p) {
                    if (p & j) continue;
                    const int q = p | j;
                    const bool upx = ((p & k) == 0);
                    const bool upy = (((p + 32) & k) == 0);  // differs only at k==32
                    u16x2 mn = pkmin(v[p], v[q]), mx = pkmax(v[p], v[q]);
                    if (upx == upy) {
                        v[p] = upx ? mn : mx;
                        v[q] = upx ? mx : mn;
                    } else {                   // k==32: slot x asc, slot y desc
                        v[p] = mk2(mn.x, mx.y);
                        v[q] = mk2(mx.x, mn.y);
                    }
                }
            }
        }
    }
}

#define SRT 66

__device__ __forceinline__ void load16(const float* __restrict__ src, int lane, float4 t[16]) {
#pragma unroll
    for (int qq = 0; qq < 16; ++qq)
        t[qq] = *(const float4*)(src + (qq * 64 + lane) * 4);
}
__device__ __forceinline__ void keys_write(u16* s, int lane, const float4 t[16]) {
#pragma unroll
    for (int qq = 0; qq < 16; ++qq) {
        int f = qq * 64 + lane, r = f >> 4, c0 = (f & 15) * 4;
        *(u16x2*)&s[r * SRT + c0]     = mk2(fkey(t[qq].x), fkey(t[qq].y));
        *(u16x2*)&s[r * SRT + c0 + 2] = mk2(fkey(t[qq].z), fkey(t[qq].w));
    }
}
__device__ __forceinline__ void col_read(const u16* s, int lane, u16x2 v[32]) {
#pragma unroll
    for (int p = 0; p < 32; ++p)
        v[p] = mk2(s[p * SRT + lane], s[(p + 32) * SRT + lane]);
}
__device__ __forceinline__ void perm_write(u16* s, int pos, const u16x2 v[32]) {
#pragma unroll
    for (int p = 0; p < 32; ++p) {
        s[p * SRT + pos]        = v[p].x;
        s[(p + 32) * SRT + pos] = v[p].y;
    }
}
__device__ __forceinline__ void row_read(const u16* s, int lane, u16x2 v[32]) {
#pragma unroll
    for (int p = 0; p < 32; ++p)
        v[p] = *(const u16x2*)&s[lane * SRT + p * 2];
}
__device__ __forceinline__ void row_write(u16* s, int lane, const u16x2 v[32]) {
#pragma unroll
    for (int p = 0; p < 32; ++p) {
        s[lane * SRT + p]      = v[p].x;
        s[lane * SRT + p + 32] = v[p].y;
    }
}
__device__ __forceinline__ void col_write(u16* s, int lane, const u16x2 v[32]) {
#pragma unroll
    for (int p = 0; p < 32; ++p) {
        s[p * SRT + lane]        = v[p].x;
        s[(p + 32) * SRT + lane] = v[p].y;
    }
}
__device__ __forceinline__ void unmap(u16x2 v[32]) {
#pragma unroll
    for (int p = 0; p < 32; ++p) {
        i16x2 sh = ((i16x2)v[p]) >> 15;        // 0xFFFF where key bit15 set (orig >=0)
        u16x2 m  = (u16x2)sh;
        u16x2 c8; c8.x = 0x8000; c8.y = 0x8000;
        v[p] = v[p] ^ ((~m) | c8);
    }
}
__device__ __forceinline__ void out_read(const u16* s, int lane, ushort4 o[16]) {
#pragma unroll
    for (int qq = 0; qq < 16; ++qq) {
        int f = qq * 64 + lane, r = f >> 4, c0 = (f & 15) * 4;
        u16x2 a = *(const u16x2*)&s[r * SRT + c0];
        u16x2 c = *(const u16x2*)&s[r * SRT + c0 + 2];
        ushort4 t; t.x = a.x; t.y = a.y; t.z = c.x; t.w = c.y;
        o[qq] = t;
    }
}
__device__ __forceinline__ void out_store(u16* __restrict__ dst, int lane, const ushort4 o[16]) {
#pragma unroll
    for (int qq = 0; qq < 16; ++qq)
        *(ushort4*)(dst + (qq * 64 + lane) * 4) = o[qq];
}

#define SORT_BLOCKS (B_DIM / 4)   // 2048: each of 2 waves sorts 2 matrices
#define CVT_BLOCKS  512

// Fused: sort blocks [0, SORT_BLOCKS) + weight-cvt blocks [SORT_BLOCKS, +CVT).
// Each sort wave processes TWO matrices through ONE shared LDS buffer:
// matrix X's boundary writes issue in the same fence-region as matrix Y's
// sortnet, so DS latency hides under VALU. Every buffer write is preceded
// by a fence that followed the last buffer read (airtight WAR).
__global__ __launch_bounds__(128)
void sort_cvt_kernel(const float* __restrict__ x, u16* __restrict__ xs,
                     const float* __restrict__ W1, unsigned short* __restrict__ W1b,
                     const float* __restrict__ W2, unsigned short* __restrict__ W2b,
                     const float* __restrict__ W3, unsigned short* __restrict__ W3b)
{
    __shared__ u16 smem[2 * 64 * SRT];

    if (blockIdx.x >= SORT_BLOCKS) {
        // ---- weight fp32 -> bf16 conversion (grid-stride) ----
        constexpr int N1 = H1_DIM * D_DIM / 4;
        constexpr int N2 = H2_DIM * H1_DIM / 4;
        constexpr int N3 = D_DIM * H2_DIM / 4;
        constexpr int NT = N1 + N2 + N3;
        int i = (blockIdx.x - SORT_BLOCKS) * 128 + threadIdx.x;
        for (; i < NT; i += CVT_BLOCKS * 128) {
            const float* src; unsigned short* dst; int j;
            if (i < N1)            { src = W1; dst = W1b; j = i; }
            else if (i < N1 + N2)  { src = W2; dst = W2b; j = i - N1; }
            else                   { src = W3; dst = W3b; j = i - N1 - N2; }
            float4 v = ((const float4*)src)[j];
            ushort4 o;
            o.x = f2bf(v.x); o.y = f2bf(v.y); o.z = f2bf(v.z); o.w = f2bf(v.w);
            ((ushort4*)dst)[j] = o;
        }
        return;
    }

    const int wave = threadIdx.x >> 6;
    const int lane = threadIdx.x & 63;
    u16* s = smem + wave * 64 * SRT;           // exclusive per-wave buffer
    const size_t m0 = (size_t)blockIdx.x * 4 + wave * 2;   // matrices m0, m0+1
    const float* srcA = x  + m0 * D_DIM;
    const float* srcB = srcA + D_DIM;
    u16*         dstA = xs + m0 * D_DIM;
    u16*         dstB = dstA + D_DIM;

    const int pos = (lane & 31) * 2 + (lane >> 5);   // permuted-row position

    float4 tA[16], tB[16];
    u16x2 va[32], vb[32];

    load16(srcA, lane, tA);
    load16(srcB, lane, tB);                    // B's loads in flight early

    // ---- stage-in A ----
    keys_write(s, lane, tA);
    WAVE_SYNC();
    // ---- sort 1 ----
    col_read(s, lane, va);
    WAVE_SYNC();
    keys_write(s, lane, tB);                   // || sortnet(va)
    sortnet(va);
    WAVE_SYNC();
    col_read(s, lane, vb);
    WAVE_SYNC();
    perm_write(s, pos, va);                    // || sortnet(vb)
    sortnet(vb);
    WAVE_SYNC();
    // ---- sort 2 (rows via permuted layout) ----
    row_read(s, lane, va);
    WAVE_SYNC();
    perm_write(s, pos, vb);                    // || sortnet(va)
    sortnet(va);
    WAVE_SYNC();
    row_read(s, lane, vb);
    WAVE_SYNC();
    row_write(s, lane, va);                    // || sortnet(vb)
    sortnet(vb);
    WAVE_SYNC();
    // ---- sort 3 ----
    col_read(s, lane, va);
    WAVE_SYNC();
    row_write(s, lane, vb);                    // || sortnet(va)+unmap
    sortnet(va);
    unmap(va);
    WAVE_SYNC();
    col_read(s, lane, vb);
    WAVE_SYNC();
    col_write(s, lane, va);                    // || sortnet(vb)+unmap
    sortnet(vb);
    unmap(vb);
    WAVE_SYNC();
    // ---- stage-out ----
    {
        ushort4 oa[16];
        out_read(s, lane, oa);
        WAVE_SYNC();
        col_write(s, lane, vb);                // || A's global stores
        out_store(dstA, lane, oa);
        WAVE_SYNC();
        ushort4 ob[16];
        out_read(s, lane, ob);
        WAVE_SYNC();
        out_store(dstB, lane, ob);
    }
}

// ---------------- bf16 MFMA GEMM: C = act(A @ W^T + bias) ------------------
// Grid is (M/BM, N/BN): A-panel siblings (same x, all y) sit at linear-id
// stride gridDim.x == 0 mod 8 -> same XCD -> shared A panel stays in one L2.
template<int BM, int BN, bool RELU, bool OUT_BF16>
__global__ __launch_bounds__(256, 2)
void gemm_mfma(const unsigned short* __restrict__ A,
               const unsigned short* __restrict__ Wt,
               const float* __restrict__ bias,
               void* __restrict__ Cout, int M, int N, int K)
{
    constexpr int BK  = 64;
    constexpr int WTM = BM / 2, WTN = BN / 2;
    constexpr int FM  = WTM / 16, FN = WTN / 16;
    __shared__ unsigned short sA[BM * BK];
    __shared__ unsigned short sB[BN * BK];

    const int tid  = threadIdx.x;
    const int wave = tid >> 6;
    const int lane = tid & 63;
    const int wm   = wave >> 1, wn = wave & 1;
    const int gm0  = blockIdx.x * BM;
    const int gn0  = blockIdx.y * BN;

    const int r_in = lane >> 3;
    const int j_in = lane & 7;

    f32x4 acc[FM][FN] = {};

    for (int k0 = 0; k0 < K; k0 += BK) {
#pragma unroll
        for (int c = 0; c < BM / 32; ++c) {
            int rb  = wave * (BM / 4) + c * 8;
            int r   = rb + r_in;
            int seg = j_in ^ (r & 7);
            const unsigned short* g = A + (size_t)(gm0 + r) * K + k0 + seg * 8;
            __builtin_amdgcn_global_load_lds(
                (const __attribute__((address_space(1))) void*)g,
                (__attribute__((address_space(3))) void*)&sA[rb * 64],
                16, 0, 0);
        }
#pragma unroll
        for (int c = 0; c < BN / 32; ++c) {
            int rb  = wave * (BN / 4) + c * 8;
            int r   = rb + r_in;
            int seg = j_in ^ (r & 7);
            const unsigned short* g = Wt + (size_t)(gn0 + r) * K + k0 + seg * 8;
            __builtin_amdgcn_global_load_lds(
                (const __attribute__((address_space(1))) void*)g,
                (__attribute__((address_space(3))) void*)&sB[rb * 64],
                16, 0, 0);
        }
        __syncthreads();

#pragma unroll
        for (int ks = 0; ks < 2; ++ks) {
            bf16x8 afr[FM], bfr[FN];
#pragma unroll
            for (int i = 0; i < FM; ++i) {
                int m   = wm * WTM + i * 16 + (lane & 15);
                int seg = (ks * 4 + (lane >> 4)) ^ (m & 7);
                afr[i] = *(const bf16x8*)&sA[m * 64 + seg * 8];
            }
#pragma unroll
            for (int j = 0; j < FN; ++j) {
                int n   = wn * WTN + j * 16 + (lane & 15);
                int seg = (ks * 4 + (lane >> 4)) ^ (n & 7);
                bfr[j] = *(const bf16x8*)&sB[n * 64 + seg * 8];
            }
#pragma unroll
            for (int i = 0; i < FM; ++i)
#pragma unroll
                for (int j = 0; j < FN; ++j)
                    acc[i][j] = __builtin_amdgcn_mfma_f32_16x16x32_bf16(
                        afr[i], bfr[j], acc[i][j], 0, 0, 0);
        }
        __syncthreads();
    }

#pragma unroll
    for (int j = 0; j < FN; ++j) {
        int n = gn0 + wn * WTN + j * 16 + (lane & 15);
        float bv = bias[n];
#pragma unroll
        for (int i = 0; i < FM; ++i) {
#pragma unroll
            for (int r = 0; r < 4; ++r) {
                int m = gm0 + wm * WTM + i * 16 + (lane >> 4) * 4 + r;
                float v = acc[i][j][r] + bv;
                if (RELU) v = fmaxf(v, 0.f);
                if (OUT_BF16)
                    ((unsigned short*)Cout)[(size_t)m * N + n] = f2bf(v);
                else
                    ((float*)Cout)[(size_t)m * N + n] = v;
            }
        }
    }
}

// ---------------------------------------------------------------------------
extern "C" void kernel_launch(void* const* d_in, const int* in_sizes, int n_in,
                              void* d_out, int out_size, void* d_ws, size_t ws_size,
                              hipStream_t stream)
{
    const float* x  = (const float*)d_in[0];
    const float* W1 = (const float*)d_in[1];
    const float* b1 = (const float*)d_in[2];
    const float* W2 = (const float*)d_in[3];
    const float* b2 = (const float*)d_in[4];
    const float* W3 = (const float*)d_in[5];
    const float* b3 = (const float*)d_in[6];
    float* out = (float*)d_out;

    // xs (bf16, 64 MB) lives in d_out; GEMM3 overwrites d_out after GEMM1 read xs.
    u16* xs = (u16*)d_out;
    char* ws = (char*)d_ws;
    unsigned short* h1b = (unsigned short*)(ws);                      //  8 MB
    unsigned short* h2b = (unsigned short*)(ws + (8u  << 20));        //  4 MB
    unsigned short* W1b = (unsigned short*)(ws + (12u << 20));        //  4 MB
    unsigned short* W2b = (unsigned short*)(ws + (16u << 20));        //  0.25 MB
    unsigned short* W3b = (unsigned short*)(ws + (17u << 20));        //  2 MB

    sort_cvt_kernel<<<SORT_BLOCKS + CVT_BLOCKS, 128, 0, stream>>>(
        x, xs, W1, W1b, W2, W2b, W3, W3b);

    // h1 = relu(xs @ W1^T + b1)  [8192 x 512, K=4096]  tile 128x64
    gemm_mfma<128, 64, true, true>
        <<<dim3(B_DIM / 128, H1_DIM / 64), 256, 0, stream>>>(
            xs, W1b, b1, h1b, B_DIM, H1_DIM, D_DIM);

    // h2 = relu(h1 @ W2^T + b2)  [8192 x 256, K=512]   tile 128x64
    gemm_mfma<128, 64, true, true>
        <<<dim3(B_DIM / 128, H2_DIM / 64), 256, 0, stream>>>(
            h1b, W2b, b2, h2b, B_DIM, H2_DIM, H1_DIM);

    // out = h2 @ W3^T + b3       [8192 x 4096, K=256]  tile 128x128
    gemm_mfma<128, 128, false, false>
        <<<dim3(B_DIM / 128, D_DIM / 128), 256, 0, stream>>>(
            h2b, W3b, b3, out, B_DIM, D_DIM, H2_DIM);
}

// Round 4
// 372.711 us; speedup vs baseline: 1.0735x; 1.0211x over previous
//
#include <hip/hip_runtime.h>
#include <hip/hip_bf16.h>

// ---------------------------------------------------------------------------
// RecursiveSortNet — bf16 MFMA pipeline, u16-key packed bitonic sort:
//   sort: round x to bf16 (monotone => commutes with sort), map to
//         order-preserving u16 keys, 3x bitonic-64 with v_pk_min/max_u16
//   h1 = relu(xs @ W1^T + b1)   bf16 MFMA, fp32 acc
//   h2 = relu(h1 @ W2^T + b2)
//   out =      h2 @ W3^T + b3   fp32 out
//
// R1: sort __syncthreads -> intra-wave lgkmcnt fences. 146 -> 91 us.
// R2: ILP-2, 2 LDS buffers: REGRESSED (118) — occupancy halved.
// R3: ILP-2, 1 shared buffer: 101 us fused (write-hiding ~neutral).
// R4: remove stage-in/out LDS phases entirely — lane c loads column c
//     DIRECTLY from global (x[r*64+lane] is coalesced: 256B/row) and
//     stores the final column directly (u16 rows, 128B contiguous).
//     DS ops/matrix 416 -> 224, boundaries 11 -> 8. k=32 bitonic level
//     via complement trick (desc == asc on ~key): -96 VALU/matrix.
//     Middle transposes keep R3-verified algebra verbatim.
// ---------------------------------------------------------------------------

#define B_DIM 8192
#define D_DIM 4096
#define H1_DIM 512
#define H2_DIM 256

typedef unsigned short u16;
typedef __attribute__((ext_vector_type(2))) unsigned short u16x2;
typedef __attribute__((ext_vector_type(2))) short i16x2;
typedef __attribute__((ext_vector_type(8))) short bf16x8;
typedef __attribute__((ext_vector_type(4))) float f32x4;

// Intra-wave LDS ordering: all prior DS ops complete before anything later
// issues; "memory" clobber stops compiler reordering memory ops across it.
#define WAVE_SYNC() asm volatile("s_waitcnt lgkmcnt(0)" ::: "memory")

__device__ __forceinline__ unsigned short f2bf(float f) {
    union { float f; unsigned u; } v{f};
    unsigned r = v.u + 0x7FFF + ((v.u >> 16) & 1);   // RNE, finite inputs
    return (unsigned short)(r >> 16);
}
// bf16 bits -> order-preserving u16 key
__device__ __forceinline__ u16 fkey(float f) {
    u16 bf = f2bf(f);
    u16 m  = (u16)(((short)bf) >> 15);               // 0xFFFF if negative
    return (u16)(bf ^ (m | 0x8000));
}
__device__ __forceinline__ u16x2 mk2(u16 a, u16 b) { u16x2 r; r.x = a; r.y = b; return r; }

#if defined(__has_builtin) && __has_builtin(__builtin_elementwise_min)
__device__ __forceinline__ u16x2 pkmin(u16x2 a, u16x2 b) { return __builtin_elementwise_min(a, b); }
__device__ __forceinline__ u16x2 pkmax(u16x2 a, u16x2 b) { return __builtin_elementwise_max(a, b); }
#else
__device__ __forceinline__ u16x2 pkmin(u16x2 a, u16x2 b) {
    return mk2(a.x < b.x ? a.x : b.x, a.y < b.y ? a.y : b.y);
}
__device__ __forceinline__ u16x2 pkmax(u16x2 a, u16x2 b) {
    return mk2(a.x > b.x ? a.x : b.x, a.y > b.y ? a.y : b.y);
}
#endif

// Bitonic sort of 64 u16 keys held as 32 packed regs, reg p = (elem p, elem p+32).
// k=32 level: slot-y needs descending; complement y-halves around the level
// (desc merge == asc merge on ~key) so every cross-reg stage is uniform.
__device__ __forceinline__ void sortnet(u16x2 v[32]) {
    const u16x2 cmask = mk2(0, 0xFFFF);
#pragma unroll
    for (int k = 2; k <= 64; k <<= 1) {
        if (k == 32) {
#pragma unroll
            for (int p = 0; p < 32; ++p) v[p] ^= cmask;
        }
#pragma unroll
        for (int j = k >> 1; j >= 1; j >>= 1) {
            if (j == 32) {                     // k==64 only, in-reg x vs y, asc
#pragma unroll
                for (int p = 0; p < 32; ++p) {
                    u16x2 sw = mk2(v[p].y, v[p].x);
                    u16x2 mn = pkmin(v[p], sw), mx = pkmax(v[p], sw);
                    v[p] = mk2(mn.x, mx.y);
                }
            } else {
#pragma unroll
                for (int p = 0; p < 32; ++p) {
                    if (p & j) continue;
                    const int q = p | j;
                    const bool up = ((p & k) == 0);   // slot-uniform (k=32 complemented)
                    u16x2 mn = pkmin(v[p], v[q]), mx = pkmax(v[p], v[q]);
                    v[p] = up ? mn : mx;
                    v[q] = up ? mx : mn;
                }
            }
        }
        if (k == 32) {
#pragma unroll
            for (int p = 0; p < 32; ++p) v[p] ^= cmask;
        }
    }
}

#define SRT 66

// lane c loads column c directly from global (coalesced: 256B per row access)
// and converts to keys, pairs (row r, row r+32).
__device__ __forceinline__ void packkeys(const float* __restrict__ src, int lane, u16x2 v[32]) {
#pragma unroll
    for (int r0 = 0; r0 < 32; r0 += 8) {
        float a[8], b[8];
#pragma unroll
        for (int i = 0; i < 8; ++i) {
            a[i] = src[(r0 + i) * 64 + lane];
            b[i] = src[(r0 + i + 32) * 64 + lane];
        }
#pragma unroll
        for (int i = 0; i < 8; ++i)
            v[r0 + i] = mk2(fkey(a[i]), fkey(b[i]));
    }
}
// lane c stores final sorted column c directly (u16 rows, 128B contiguous).
__device__ __forceinline__ void storeout(u16* __restrict__ dst, int lane, const u16x2 v[32]) {
#pragma unroll
    for (int r = 0; r < 32; ++r) {
        dst[r * 64 + lane]        = v[r].x;
        dst[(r + 32) * 64 + lane] = v[r].y;   // d16_hi store
    }
}

// --- middle-transpose helpers (verbatim from R3, verified) ---
__device__ __forceinline__ void perm_write(u16* s, int pos, const u16x2 v[32]) {
#pragma unroll
    for (int p = 0; p < 32; ++p) {
        s[p * SRT + pos]        = v[p].x;
        s[(p + 32) * SRT + pos] = v[p].y;
    }
}
__device__ __forceinline__ void row_read(const u16* s, int lane, u16x2 v[32]) {
#pragma unroll
    for (int p = 0; p < 32; ++p)
        v[p] = *(const u16x2*)&s[lane * SRT + p * 2];
}
__device__ __forceinline__ void row_write(u16* s, int lane, const u16x2 v[32]) {
#pragma unroll
    for (int p = 0; p < 32; ++p) {
        s[lane * SRT + p]      = v[p].x;
        s[lane * SRT + p + 32] = v[p].y;
    }
}
__device__ __forceinline__ void col_read(const u16* s, int lane, u16x2 v[32]) {
#pragma unroll
    for (int p = 0; p < 32; ++p)
        v[p] = mk2(s[p * SRT + lane], s[(p + 32) * SRT + lane]);
}
__device__ __forceinline__ void unmap(u16x2 v[32]) {
#pragma unroll
    for (int p = 0; p < 32; ++p) {
        i16x2 sh = ((i16x2)v[p]) >> 15;        // 0xFFFF where key bit15 set (orig >=0)
        u16x2 m  = (u16x2)sh;
        u16x2 c8; c8.x = 0x8000; c8.y = 0x8000;
        v[p] = v[p] ^ ((~m) | c8);
    }
}

#define SORT_BLOCKS (B_DIM / 4)   // 2048: 2 waves/block, 2 matrices/wave
#define CVT_BLOCKS  512

// Fused: sort blocks [0, SORT_BLOCKS) + weight-cvt blocks [SORT_BLOCKS, +CVT).
// Per wave: 2 matrices time-share ONE LDS buffer; every buffer write is
// preceded by a fence that followed the last buffer read (airtight WAR);
// each write phase issues alongside the other matrix's sortnet.
__global__ __launch_bounds__(128)
void sort_cvt_kernel(const float* __restrict__ x, u16* __restrict__ xs,
                     const float* __restrict__ W1, unsigned short* __restrict__ W1b,
                     const float* __restrict__ W2, unsigned short* __restrict__ W2b,
                     const float* __restrict__ W3, unsigned short* __restrict__ W3b)
{
    __shared__ u16 smem[2 * 64 * SRT];

    if (blockIdx.x >= SORT_BLOCKS) {
        // ---- weight fp32 -> bf16 conversion (grid-stride) ----
        constexpr int N1 = H1_DIM * D_DIM / 4;
        constexpr int N2 = H2_DIM * H1_DIM / 4;
        constexpr int N3 = D_DIM * H2_DIM / 4;
        constexpr int NT = N1 + N2 + N3;
        int i = (blockIdx.x - SORT_BLOCKS) * 128 + threadIdx.x;
        for (; i < NT; i += CVT_BLOCKS * 128) {
            const float* src; unsigned short* dst; int j;
            if (i < N1)            { src = W1; dst = W1b; j = i; }
            else if (i < N1 + N2)  { src = W2; dst = W2b; j = i - N1; }
            else                   { src = W3; dst = W3b; j = i - N1 - N2; }
            float4 v = ((const float4*)src)[j];
            ushort4 o;
            o.x = f2bf(v.x); o.y = f2bf(v.y); o.z = f2bf(v.z); o.w = f2bf(v.w);
            ((ushort4*)dst)[j] = o;
        }
        return;
    }

    const int wave = threadIdx.x >> 6;
    const int lane = threadIdx.x & 63;
    u16* s = smem + wave * 64 * SRT;           // exclusive per-wave buffer
    const size_t m0 = (size_t)blockIdx.x * 4 + wave * 2;   // matrices m0, m0+1
    const float* srcA = x  + m0 * D_DIM;
    const float* srcB = srcA + D_DIM;
    u16*         dstA = xs + m0 * D_DIM;
    u16*         dstB = dstA + D_DIM;

    const int pos = (lane & 31) * 2 + (lane >> 5);   // permuted-row position

    u16x2 va[32], vb[32];

    // ---- sort 1 (columns): direct global stage-in, no LDS ----
    packkeys(srcA, lane, va);
    sortnet(va);
    packkeys(srcB, lane, vb);
    perm_write(s, pos, va);
    sortnet(vb);
    WAVE_SYNC();                 // A's transpose-writes done
    row_read(s, lane, va);
    WAVE_SYNC();                 // A's reads done -> buffer free
    perm_write(s, pos, vb);
    sortnet(va);                 // sort 2 A (rows)  || B's writes drain
    WAVE_SYNC();
    row_read(s, lane, vb);
    WAVE_SYNC();
    row_write(s, lane, va);
    sortnet(vb);                 // sort 2 B  || A's writes drain
    WAVE_SYNC();
    col_read(s, lane, va);
    WAVE_SYNC();
    row_write(s, lane, vb);
    sortnet(va);                 // sort 3 A (columns)  || B's writes drain
    unmap(va);
    WAVE_SYNC();
    col_read(s, lane, vb);
    storeout(dstA, lane, va);    // direct global stage-out A
    sortnet(vb);                 // sort 3 B
    unmap(vb);
    storeout(dstB, lane, vb);    // direct global stage-out B
}

// ---------------- bf16 MFMA GEMM: C = act(A @ W^T + bias) ------------------
// Grid is (M/BM, N/BN): A-panel siblings (same x, all y) sit at linear-id
// stride gridDim.x == 0 mod 8 -> same XCD -> shared A panel stays in one L2.
template<int BM, int BN, bool RELU, bool OUT_BF16>
__global__ __launch_bounds__(256, 2)
void gemm_mfma(const unsigned short* __restrict__ A,
               const unsigned short* __restrict__ Wt,
               const float* __restrict__ bias,
               void* __restrict__ Cout, int M, int N, int K)
{
    constexpr int BK  = 64;
    constexpr int WTM = BM / 2, WTN = BN / 2;
    constexpr int FM  = WTM / 16, FN = WTN / 16;
    __shared__ unsigned short sA[BM * BK];
    __shared__ unsigned short sB[BN * BK];

    const int tid  = threadIdx.x;
    const int wave = tid >> 6;
    const int lane = tid & 63;
    const int wm   = wave >> 1, wn = wave & 1;
    const int gm0  = blockIdx.x * BM;
    const int gn0  = blockIdx.y * BN;

    const int r_in = lane >> 3;
    const int j_in = lane & 7;

    f32x4 acc[FM][FN] = {};

    for (int k0 = 0; k0 < K; k0 += BK) {
#pragma unroll
        for (int c = 0; c < BM / 32; ++c) {
            int rb  = wave * (BM / 4) + c * 8;
            int r   = rb + r_in;
            int seg = j_in ^ (r & 7);
            const unsigned short* g = A + (size_t)(gm0 + r) * K + k0 + seg * 8;
            __builtin_amdgcn_global_load_lds(
                (const __attribute__((address_space(1))) void*)g,
                (__attribute__((address_space(3))) void*)&sA[rb * 64],
                16, 0, 0);
        }
#pragma unroll
        for (int c = 0; c < BN / 32; ++c) {
            int rb  = wave * (BN / 4) + c * 8;
            int r   = rb + r_in;
            int seg = j_in ^ (r & 7);
            const unsigned short* g = Wt + (size_t)(gn0 + r) * K + k0 + seg * 8;
            __builtin_amdgcn_global_load_lds(
                (const __attribute__((address_space(1))) void*)g,
                (__attribute__((address_space(3))) void*)&sB[rb * 64],
                16, 0, 0);
        }
        __syncthreads();

#pragma unroll
        for (int ks = 0; ks < 2; ++ks) {
            bf16x8 afr[FM], bfr[FN];
#pragma unroll
            for (int i = 0; i < FM; ++i) {
                int m   = wm * WTM + i * 16 + (lane & 15);
                int seg = (ks * 4 + (lane >> 4)) ^ (m & 7);
                afr[i] = *(const bf16x8*)&sA[m * 64 + seg * 8];
            }
#pragma unroll
            for (int j = 0; j < FN; ++j) {
                int n   = wn * WTN + j * 16 + (lane & 15);
                int seg = (ks * 4 + (lane >> 4)) ^ (n & 7);
                bfr[j] = *(const bf16x8*)&sB[n * 64 + seg * 8];
            }
#pragma unroll
            for (int i = 0; i < FM; ++i)
#pragma unroll
                for (int j = 0; j < FN; ++j)
                    acc[i][j] = __builtin_amdgcn_mfma_f32_16x16x32_bf16(
                        afr[i], bfr[j], acc[i][j], 0, 0, 0);
        }
        __syncthreads();
    }

#pragma unroll
    for (int j = 0; j < FN; ++j) {
        int n = gn0 + wn * WTN + j * 16 + (lane & 15);
        float bv = bias[n];
#pragma unroll
        for (int i = 0; i < FM; ++i) {
#pragma unroll
            for (int r = 0; r < 4; ++r) {
                int m = gm0 + wm * WTM + i * 16 + (lane >> 4) * 4 + r;
                float v = acc[i][j][r] + bv;
                if (RELU) v = fmaxf(v, 0.f);
                if (OUT_BF16)
                    ((unsigned short*)Cout)[(size_t)m * N + n] = f2bf(v);
                else
                    ((float*)Cout)[(size_t)m * N + n] = v;
            }
        }
    }
}

// ---------------------------------------------------------------------------
extern "C" void kernel_launch(void* const* d_in, const int* in_sizes, int n_in,
                              void* d_out, int out_size, void* d_ws, size_t ws_size,
                              hipStream_t stream)
{
    const float* x  = (const float*)d_in[0];
    const float* W1 = (const float*)d_in[1];
    const float* b1 = (const float*)d_in[2];
    const float* W2 = (const float*)d_in[3];
    const float* b2 = (const float*)d_in[4];
    const float* W3 = (const float*)d_in[5];
    const float* b3 = (const float*)d_in[6];
    float* out = (float*)d_out;

    // xs (bf16, 64 MB) lives in d_out; GEMM3 overwrites d_out after GEMM1 read xs.
    u16* xs = (u16*)d_out;
    char* ws = (char*)d_ws;
    unsigned short* h1b = (unsigned short*)(ws);                      //  8 MB
    unsigned short* h2b = (unsigned short*)(ws + (8u  << 20));        //  4 MB
    unsigned short* W1b = (unsigned short*)(ws + (12u << 20));        //  4 MB
    unsigned short* W2b = (unsigned short*)(ws + (16u << 20));        //  0.25 MB
    unsigned short* W3b = (unsigned short*)(ws + (17u << 20));        //  2 MB

    sort_cvt_kernel<<<SORT_BLOCKS + CVT_BLOCKS, 128, 0, stream>>>(
        x, xs, W1, W1b, W2, W2b, W3, W3b);

    // h1 = relu(xs @ W1^T + b1)  [8192 x 512, K=4096]  tile 128x64
    gemm_mfma<128, 64, true, true>
        <<<dim3(B_DIM / 128, H1_DIM / 64), 256, 0, stream>>>(
            xs, W1b, b1, h1b, B_DIM, H1_DIM, D_DIM);

    // h2 = relu(h1 @ W2^T + b2)  [8192 x 256, K=512]   tile 128x64
    gemm_mfma<128, 64, true, true>
        <<<dim3(B_DIM / 128, H2_DIM / 64), 256, 0, stream>>>(
            h1b, W2b, b2, h2b, B_DIM, H2_DIM, H1_DIM);

    // out = h2 @ W3^T + b3       [8192 x 4096, K=256]  tile 128x128
    gemm_mfma<128, 128, false, false>
        <<<dim3(B_DIM / 128, D_DIM / 128), 256, 0, stream>>>(
            h2b, W3b, b3, out, B_DIM, D_DIM, H2_DIM);
}

// Round 5
// 369.852 us; speedup vs baseline: 1.0818x; 1.0077x over previous
//
#include <hip/hip_runtime.h>
#include <hip/hip_bf16.h>

// ---------------------------------------------------------------------------
// RecursiveSortNet — bf16 MFMA pipeline, u16-key packed bitonic sort:
//   sort: round x to bf16 (monotone => commutes with sort), map to
//         order-preserving u16 keys, 3x bitonic-64 with v_pk_min/max_u16
//   h1 = relu(xs @ W1^T + b1)   bf16 MFMA, fp32 acc
//   h2 = relu(h1 @ W2^T + b2)
//   out =      h2 @ W3^T + b3   fp32 out
//
// R1: sort __syncthreads -> intra-wave lgkmcnt fences. 146 -> 91 us.
// R2: ILP-2, 2 LDS buffers: REGRESSED (118) — occupancy halved.
// R3: ILP-2, 1 shared buffer: 101 us fused.
// R4: direct global stage-in/out (no LDS round-trip); complement trick at
//     k=32. Sort now below the 95us fill dispatches (invisible in top-5).
// R5: symmetric transposes — T2 now uses the same (perm_write + packed
//     row_read) pair as T1 instead of (row_write + 64 scalar col reads).
//     By symmetry the writer lane=row r with the SAME pos formula yields a
//     column-major-permuted layout whose packed b32 row_read by lane=c is
//     exactly sort-3's required register layout. DS ops 224 -> 192/matrix,
//     fences 8 -> 7, col_read + d16 merges deleted.
// ---------------------------------------------------------------------------

#define B_DIM 8192
#define D_DIM 4096
#define H1_DIM 512
#define H2_DIM 256

typedef unsigned short u16;
typedef __attribute__((ext_vector_type(2))) unsigned short u16x2;
typedef __attribute__((ext_vector_type(2))) short i16x2;
typedef __attribute__((ext_vector_type(8))) short bf16x8;
typedef __attribute__((ext_vector_type(4))) float f32x4;

// Intra-wave LDS ordering: all prior DS ops complete before anything later
// issues; "memory" clobber stops compiler reordering memory ops across it.
#define WAVE_SYNC() asm volatile("s_waitcnt lgkmcnt(0)" ::: "memory")

__device__ __forceinline__ unsigned short f2bf(float f) {
    union { float f; unsigned u; } v{f};
    unsigned r = v.u + 0x7FFF + ((v.u >> 16) & 1);   // RNE, finite inputs
    return (unsigned short)(r >> 16);
}
// bf16 bits -> order-preserving u16 key
__device__ __forceinline__ u16 fkey(float f) {
    u16 bf = f2bf(f);
    u16 m  = (u16)(((short)bf) >> 15);               // 0xFFFF if negative
    return (u16)(bf ^ (m | 0x8000));
}
__device__ __forceinline__ u16x2 mk2(u16 a, u16 b) { u16x2 r; r.x = a; r.y = b; return r; }

#if defined(__has_builtin) && __has_builtin(__builtin_elementwise_min)
__device__ __forceinline__ u16x2 pkmin(u16x2 a, u16x2 b) { return __builtin_elementwise_min(a, b); }
__device__ __forceinline__ u16x2 pkmax(u16x2 a, u16x2 b) { return __builtin_elementwise_max(a, b); }
#else
__device__ __forceinline__ u16x2 pkmin(u16x2 a, u16x2 b) {
    return mk2(a.x < b.x ? a.x : b.x, a.y < b.y ? a.y : b.y);
}
__device__ __forceinline__ u16x2 pkmax(u16x2 a, u16x2 b) {
    return mk2(a.x > b.x ? a.x : b.x, a.y > b.y ? a.y : b.y);
}
#endif

// Bitonic sort of 64 u16 keys held as 32 packed regs, reg p = (elem p, elem p+32).
// k=32 level: slot-y needs descending; complement y-halves around the level
// (desc merge == asc merge on ~key) so every cross-reg stage is uniform.
__device__ __forceinline__ void sortnet(u16x2 v[32]) {
    const u16x2 cmask = mk2(0, 0xFFFF);
#pragma unroll
    for (int k = 2; k <= 64; k <<= 1) {
        if (k == 32) {
#pragma unroll
            for (int p = 0; p < 32; ++p) v[p] ^= cmask;
        }
#pragma unroll
        for (int j = k >> 1; j >= 1; j >>= 1) {
            if (j == 32) {                     // k==64 only, in-reg x vs y, asc
#pragma unroll
                for (int p = 0; p < 32; ++p) {
                    u16x2 sw = mk2(v[p].y, v[p].x);
                    u16x2 mn = pkmin(v[p], sw), mx = pkmax(v[p], sw);
                    v[p] = mk2(mn.x, mx.y);
                }
            } else {
#pragma unroll
                for (int p = 0; p < 32; ++p) {
                    if (p & j) continue;
                    const int q = p | j;
                    const bool up = ((p & k) == 0);   // slot-uniform (k=32 complemented)
                    u16x2 mn = pkmin(v[p], v[q]), mx = pkmax(v[p], v[q]);
                    v[p] = up ? mn : mx;
                    v[q] = up ? mx : mn;
                }
            }
        }
        if (k == 32) {
#pragma unroll
            for (int p = 0; p < 32; ++p) v[p] ^= cmask;
        }
    }
}

#define SRT 66

// lane c loads column c directly from global (coalesced: 256B per row access)
// and converts to keys, pairs (row r, row r+32).
__device__ __forceinline__ void packkeys(const float* __restrict__ src, int lane, u16x2 v[32]) {
#pragma unroll
    for (int r0 = 0; r0 < 32; r0 += 8) {
        float a[8], b[8];
#pragma unroll
        for (int i = 0; i < 8; ++i) {
            a[i] = src[(r0 + i) * 64 + lane];
            b[i] = src[(r0 + i + 32) * 64 + lane];
        }
#pragma unroll
        for (int i = 0; i < 8; ++i)
            v[r0 + i] = mk2(fkey(a[i]), fkey(b[i]));
    }
}
// lane c stores final sorted column c directly (u16 rows, 128B contiguous).
__device__ __forceinline__ void storeout(u16* __restrict__ dst, int lane, const u16x2 v[32]) {
#pragma unroll
    for (int r = 0; r < 32; ++r) {
        dst[r * 64 + lane]        = v[r].x;
        dst[(r + 32) * 64 + lane] = v[r].y;   // d16_hi store
    }
}

// --- symmetric transpose pair (verified algebra, used for BOTH transposes):
// writer: reg p = (slot x -> LDS-row p, slot y -> LDS-row p+32), position
// pos = (lane&31)*2 + (lane>>5) within the row.
// reader: lane L reads packed b32 pairs from LDS-row L: reg p = (pos 2p, 2p+1).
// T1: writer lane=col c (rows in regs) -> LDS-row = matrix row; reader
//     lane=row r gets (col p, col p+32).
// T2: writer lane=row r (cols in regs) -> LDS-row = matrix col; reader
//     lane=col c gets (row p, row p+32). Same code by symmetry.
__device__ __forceinline__ void perm_write(u16* s, int pos, const u16x2 v[32]) {
#pragma unroll
    for (int p = 0; p < 32; ++p) {
        s[p * SRT + pos]        = v[p].x;
        s[(p + 32) * SRT + pos] = v[p].y;
    }
}
__device__ __forceinline__ void row_read(const u16* s, int lane, u16x2 v[32]) {
#pragma unroll
    for (int p = 0; p < 32; ++p)
        v[p] = *(const u16x2*)&s[lane * SRT + p * 2];
}
__device__ __forceinline__ void unmap(u16x2 v[32]) {
#pragma unroll
    for (int p = 0; p < 32; ++p) {
        i16x2 sh = ((i16x2)v[p]) >> 15;        // 0xFFFF where key bit15 set (orig >=0)
        u16x2 m  = (u16x2)sh;
        u16x2 c8; c8.x = 0x8000; c8.y = 0x8000;
        v[p] = v[p] ^ ((~m) | c8);
    }
}

#define SORT_BLOCKS (B_DIM / 4)   // 2048: 2 waves/block, 2 matrices/wave
#define CVT_BLOCKS  512

// Fused: sort blocks [0, SORT_BLOCKS) + weight-cvt blocks [SORT_BLOCKS, +CVT).
// Per wave: 2 matrices time-share ONE LDS buffer; every buffer write is
// preceded by a fence that followed the last buffer read (airtight WAR);
// each write phase issues alongside the other matrix's sortnet.
__global__ __launch_bounds__(128)
void sort_cvt_kernel(const float* __restrict__ x, u16* __restrict__ xs,
                     const float* __restrict__ W1, unsigned short* __restrict__ W1b,
                     const float* __restrict__ W2, unsigned short* __restrict__ W2b,
                     const float* __restrict__ W3, unsigned short* __restrict__ W3b)
{
    __shared__ u16 smem[2 * 64 * SRT];

    if (blockIdx.x >= SORT_BLOCKS) {
        // ---- weight fp32 -> bf16 conversion (grid-stride) ----
        constexpr int N1 = H1_DIM * D_DIM / 4;
        constexpr int N2 = H2_DIM * H1_DIM / 4;
        constexpr int N3 = D_DIM * H2_DIM / 4;
        constexpr int NT = N1 + N2 + N3;
        int i = (blockIdx.x - SORT_BLOCKS) * 128 + threadIdx.x;
        for (; i < NT; i += CVT_BLOCKS * 128) {
            const float* src; unsigned short* dst; int j;
            if (i < N1)            { src = W1; dst = W1b; j = i; }
            else if (i < N1 + N2)  { src = W2; dst = W2b; j = i - N1; }
            else                   { src = W3; dst = W3b; j = i - N1 - N2; }
            float4 v = ((const float4*)src)[j];
            ushort4 o;
            o.x = f2bf(v.x); o.y = f2bf(v.y); o.z = f2bf(v.z); o.w = f2bf(v.w);
            ((ushort4*)dst)[j] = o;
        }
        return;
    }

    const int wave = threadIdx.x >> 6;
    const int lane = threadIdx.x & 63;
    u16* s = smem + wave * 64 * SRT;           // exclusive per-wave buffer
    const size_t m0 = (size_t)blockIdx.x * 4 + wave * 2;   // matrices m0, m0+1
    const float* srcA = x  + m0 * D_DIM;
    const float* srcB = srcA + D_DIM;
    u16*         dstA = xs + m0 * D_DIM;
    u16*         dstB = dstA + D_DIM;

    const int pos = (lane & 31) * 2 + (lane >> 5);   // permuted position

    u16x2 va[32], vb[32];

    // ---- sort 1 (columns): direct global stage-in, no LDS ----
    packkeys(srcA, lane, va);
    sortnet(va);
    packkeys(srcB, lane, vb);
    perm_write(s, pos, va);      // T1 A
    sortnet(vb);                 // covers A's write drain
    WAVE_SYNC();
    row_read(s, lane, va);
    WAVE_SYNC();                 // A reads done -> buffer free
    perm_write(s, pos, vb);      // T1 B
    sortnet(va);                 // sort 2 A (rows)  || B's writes drain
    WAVE_SYNC();
    row_read(s, lane, vb);
    WAVE_SYNC();
    perm_write(s, pos, va);      // T2 A (same code by symmetry)
    sortnet(vb);                 // sort 2 B  || A's writes drain
    WAVE_SYNC();
    row_read(s, lane, va);
    WAVE_SYNC();
    perm_write(s, pos, vb);      // T2 B
    sortnet(va);                 // sort 3 A (columns)  || B's writes drain
    unmap(va);
    storeout(dstA, lane, va);    // direct global stage-out A
    WAVE_SYNC();
    row_read(s, lane, vb);
    sortnet(vb);                 // sort 3 B
    unmap(vb);
    storeout(dstB, lane, vb);    // direct global stage-out B
}

// ---------------- bf16 MFMA GEMM: C = act(A @ W^T + bias) ------------------
// Grid is (M/BM, N/BN): A-panel siblings (same x, all y) sit at linear-id
// stride gridDim.x == 0 mod 8 -> same XCD -> shared A panel stays in one L2.
template<int BM, int BN, bool RELU, bool OUT_BF16>
__global__ __launch_bounds__(256, 2)
void gemm_mfma(const unsigned short* __restrict__ A,
               const unsigned short* __restrict__ Wt,
               const float* __restrict__ bias,
               void* __restrict__ Cout, int M, int N, int K)
{
    constexpr int BK  = 64;
    constexpr int WTM = BM / 2, WTN = BN / 2;
    constexpr int FM  = WTM / 16, FN = WTN / 16;
    __shared__ unsigned short sA[BM * BK];
    __shared__ unsigned short sB[BN * BK];

    const int tid  = threadIdx.x;
    const int wave = tid >> 6;
    const int lane = tid & 63;
    const int wm   = wave >> 1, wn = wave & 1;
    const int gm0  = blockIdx.x * BM;
    const int gn0  = blockIdx.y * BN;

    const int r_in = lane >> 3;
    const int j_in = lane & 7;

    f32x4 acc[FM][FN] = {};

    for (int k0 = 0; k0 < K; k0 += BK) {
#pragma unroll
        for (int c = 0; c < BM / 32; ++c) {
            int rb  = wave * (BM / 4) + c * 8;
            int r   = rb + r_in;
            int seg = j_in ^ (r & 7);
            const unsigned short* g = A + (size_t)(gm0 + r) * K + k0 + seg * 8;
            __builtin_amdgcn_global_load_lds(
                (const __attribute__((address_space(1))) void*)g,
                (__attribute__((address_space(3))) void*)&sA[rb * 64],
                16, 0, 0);
        }
#pragma unroll
        for (int c = 0; c < BN / 32; ++c) {
            int rb  = wave * (BN / 4) + c * 8;
            int r   = rb + r_in;
            int seg = j_in ^ (r & 7);
            const unsigned short* g = Wt + (size_t)(gn0 + r) * K + k0 + seg * 8;
            __builtin_amdgcn_global_load_lds(
                (const __attribute__((address_space(1))) void*)g,
                (__attribute__((address_space(3))) void*)&sB[rb * 64],
                16, 0, 0);
        }
        __syncthreads();

#pragma unroll
        for (int ks = 0; ks < 2; ++ks) {
            bf16x8 afr[FM], bfr[FN];
#pragma unroll
            for (int i = 0; i < FM; ++i) {
                int m   = wm * WTM + i * 16 + (lane & 15);
                int seg = (ks * 4 + (lane >> 4)) ^ (m & 7);
                afr[i] = *(const bf16x8*)&sA[m * 64 + seg * 8];
            }
#pragma unroll
            for (int j = 0; j < FN; ++j) {
                int n   = wn * WTN + j * 16 + (lane & 15);
                int seg = (ks * 4 + (lane >> 4)) ^ (n & 7);
                bfr[j] = *(const bf16x8*)&sB[n * 64 + seg * 8];
            }
#pragma unroll
            for (int i = 0; i < FM; ++i)
#pragma unroll
                for (int j = 0; j < FN; ++j)
                    acc[i][j] = __builtin_amdgcn_mfma_f32_16x16x32_bf16(
                        afr[i], bfr[j], acc[i][j], 0, 0, 0);
        }
        __syncthreads();
    }

#pragma unroll
    for (int j = 0; j < FN; ++j) {
        int n = gn0 + wn * WTN + j * 16 + (lane & 15);
        float bv = bias[n];
#pragma unroll
        for (int i = 0; i < FM; ++i) {
#pragma unroll
            for (int r = 0; r < 4; ++r) {
                int m = gm0 + wm * WTM + i * 16 + (lane >> 4) * 4 + r;
                float v = acc[i][j][r] + bv;
                if (RELU) v = fmaxf(v, 0.f);
                if (OUT_BF16)
                    ((unsigned short*)Cout)[(size_t)m * N + n] = f2bf(v);
                else
                    ((float*)Cout)[(size_t)m * N + n] = v;
            }
        }
    }
}

// ---------------------------------------------------------------------------
extern "C" void kernel_launch(void* const* d_in, const int* in_sizes, int n_in,
                              void* d_out, int out_size, void* d_ws, size_t ws_size,
                              hipStream_t stream)
{
    const float* x  = (const float*)d_in[0];
    const float* W1 = (const float*)d_in[1];
    const float* b1 = (const float*)d_in[2];
    const float* W2 = (const float*)d_in[3];
    const float* b2 = (const float*)d_in[4];
    const float* W3 = (const float*)d_in[5];
    const float* b3 = (const float*)d_in[6];
    float* out = (float*)d_out;

    // xs (bf16, 64 MB) lives in d_out; GEMM3 overwrites d_out after GEMM1 read xs.
    u16* xs = (u16*)d_out;
    char* ws = (char*)d_ws;
    unsigned short* h1b = (unsigned short*)(ws);                      //  8 MB
    unsigned short* h2b = (unsigned short*)(ws + (8u  << 20));        //  4 MB
    unsigned short* W1b = (unsigned short*)(ws + (12u << 20));        //  4 MB
    unsigned short* W2b = (unsigned short*)(ws + (16u << 20));        //  0.25 MB
    unsigned short* W3b = (unsigned short*)(ws + (17u << 20));        //  2 MB

    sort_cvt_kernel<<<SORT_BLOCKS + CVT_BLOCKS, 128, 0, stream>>>(
        x, xs, W1, W1b, W2, W2b, W3, W3b);

    // h1 = relu(xs @ W1^T + b1)  [8192 x 512, K=4096]  tile 128x64
    gemm_mfma<128, 64, true, true>
        <<<dim3(B_DIM / 128, H1_DIM / 64), 256, 0, stream>>>(
            xs, W1b, b1, h1b, B_DIM, H1_DIM, D_DIM);

    // h2 = relu(h1 @ W2^T + b2)  [8192 x 256, K=512]   tile 128x64
    gemm_mfma<128, 64, true, true>
        <<<dim3(B_DIM / 128, H2_DIM / 64), 256, 0, stream>>>(
            h1b, W2b, b2, h2b, B_DIM, H2_DIM, H1_DIM);

    // out = h2 @ W3^T + b3       [8192 x 4096, K=256]  tile 128x128
    gemm_mfma<128, 128, false, false>
        <<<dim3(B_DIM / 128, D_DIM / 128), 256, 0, stream>>>(
            h2b, W3b, b3, out, B_DIM, D_DIM, H2_DIM);
}